// Round 21
// baseline (71.770 us; speedup 1.0000x reference)
//
#include <hip/hip_runtime.h>

typedef unsigned long long u64;
typedef unsigned int u32;
typedef unsigned short u16;

#define N_DET 4096
#define NW 64               // 4096 bits = 64 u64 words
#define IOU_TR 0.3f
#define SCORE_TR 0.1f
#define EPS 1e-9f
#define SB 96               // rows per super-batch (3 loader waves x 32)

// ---------------------------------------------------------------------------
// ws layout (R20):
//   rows  : 4096*8 f32    (sorted detection rows)        128 KB
//   ssc   : 4096 f32      (sorted scores, compact)        16 KB
//   soaLO : 4096 float4   (lox,loy,loz,vol)               64 KB
//   soaHI : 4096 float4   (hix,hiy,hiz,0)                 64 KB
//   A     : 64 u64        (bit i = row i nonempty)
//   keep  : 64 u64
//   Trm   : 4096*64 u64   row-major; nonempty rows written; row 4095 zeroed.
// 4 dispatches: k_sort, k_sup (R20 LDS-tiled), k_scan (producer-consumer,
// SB=96 + BATCH-PARALLEL consumer: stable-act test / applied-accumulate /
// conflict-check / rare serial redo), k_out.
// LEDGER: R20 49.3 best. Refuted: ov-branch sup (R7/R9), edge-walk (R11),
// 2-row sup (R12), mirror scan (R14), last-block fusion (R7/R13), 1-block
// output (R10), spin-flag co-dispatch (R19). R16 batch was neutral when
// loads were critical; consumer chain is now critical => retest (regime gate).
// ---------------------------------------------------------------------------

__device__ __forceinline__ u64 rl64(u64 v, int l) {
    unsigned lo = __builtin_amdgcn_readlane((unsigned)v, l);
    unsigned hi = __builtin_amdgcn_readlane((unsigned)(v >> 32), l);
    return ((u64)hi << 32) | lo;
}

// K1: stable descending rank sort (R20-exact) + zero A + zero Trm row 4095.
__global__ void __launch_bounds__(256) k_sort(const float* __restrict__ res,
                                              float* __restrict__ rows,
                                              float* __restrict__ ssc,
                                              float4* __restrict__ soaLO,
                                              float4* __restrict__ soaHI,
                                              u64* __restrict__ A,
                                              u64* __restrict__ Trm) {
    __shared__ float s[N_DET];
    int tid = threadIdx.x;
    if (blockIdx.x == 0) {
        if (tid < 64) A[tid] = 0ull;
        if (tid >= 64 && tid < 128)                 // sentinel row: all zeros
            Trm[(size_t)4095 * NW + (tid - 64)] = 0ull;
    }
    for (int j = tid; j < N_DET; j += 256) s[j] = res[j * 8];
    __syncthreads();
    int r = tid >> 4, c = tid & 15;
    int gi = blockIdx.x * 16 + r;
    float sc = s[gi];
    int part = 0;
    int j0 = c * 256;
    for (int j = j0; j < j0 + 256; ++j) {
        float sj = s[j];
        part += (sj > sc) || (sj == sc && j < gi);
    }
    part += __shfl_xor(part, 1, 64);
    part += __shfl_xor(part, 2, 64);
    part += __shfl_xor(part, 4, 64);
    part += __shfl_xor(part, 8, 64);
    if (c == 0) {
        int rank = part;
        float4 a = *(const float4*)(res + gi * 8);
        float4 b = *(const float4*)(res + gi * 8 + 4);
        *(float4*)(rows + rank * 8)     = a;
        *(float4*)(rows + rank * 8 + 4) = b;
        ssc[rank] = a.x;
        // a = (score, class, cx, cy); b = (cz, dx, dy, dz)
        float cx = a.z, cy = a.w, cz = b.x, dx = b.y, dy = b.z, dz = b.w;
        soaLO[rank] = make_float4(cx - dx * 0.5f, cy - dy * 0.5f,
                                  cz - dz * 0.5f, (dx * dy) * dz); // vol in .w
        soaHI[rank] = make_float4(cx + dx * 0.5f, cy + dy * 0.5f,
                                  cz + dz * 0.5f, 0.0f);
    }
}

// K2: suppression rows, LDS-TILED (R20-exact).
__global__ void __launch_bounds__(256) k_sup(const float4* __restrict__ soaLO,
                                             const float4* __restrict__ soaHI,
                                             const float* __restrict__ ssc,
                                             u64* __restrict__ Trm,
                                             u64* __restrict__ A) {
    __shared__ float s_b[2][7][4][64];   // [buf][field][word][box] 14 KB
    const int tid = threadIdx.x;
    const int wv = tid >> 6;
    const int lane = tid & 63;
    const int i0 = blockIdx.x * 4;
    const int i = i0 + wv;
    const int w0 = i0 >> 6;              // block-uniform start word
    const bool valid = ssc[i] >= SCORE_TR;   // wave-uniform (store guard)
    float4 iLO = soaLO[i];               // (lox,loy,loz,vol)
    float4 iHI = soaHI[i];               // (hix,hiy,hiz,-)
    u64 rowword = 0, rowOr = 0;

    {
        int j = w0 * 64 + tid;
        int c = tid >> 6, l = tid & 63;
        if (j < N_DET) {
            float4 lo = soaLO[j], hi = soaHI[j];
            s_b[0][0][c][l] = lo.x; s_b[0][1][c][l] = lo.y;
            s_b[0][2][c][l] = lo.z; s_b[0][3][c][l] = lo.w;
            s_b[0][4][c][l] = hi.x; s_b[0][5][c][l] = hi.y;
            s_b[0][6][c][l] = hi.z;
        }
    }
    __syncthreads();

    for (int w = w0; w < NW; w += 4) {
        const int cur = ((w - w0) >> 2) & 1;
        const int jn = (w + 4) * 64 + tid;
        const bool inb = jn < N_DET;
        float4 nlo = make_float4(0.f, 0.f, 0.f, 0.f);
        float4 nhi = make_float4(0.f, 0.f, 0.f, 0.f);
        if (inb) { nlo = soaLO[jn]; nhi = soaHI[jn]; }

        const int nc = (NW - w < 4) ? (NW - w) : 4;
        for (int c = 0; c < nc; ++c) {   // block-uniform bound
            int jj = (w + c) * 64 + lane;
            float lox = s_b[cur][0][c][lane], loy = s_b[cur][1][c][lane];
            float loz = s_b[cur][2][c][lane], vol = s_b[cur][3][c][lane];
            float hix = s_b[cur][4][c][lane], hiy = s_b[cur][5][c][lane];
            float hiz = s_b[cur][6][c][lane];
            float ix = fminf(iHI.x, hix) - fmaxf(iLO.x, lox); ix = fmaxf(ix, 0.f);
            float iy = fminf(iHI.y, hiy) - fmaxf(iLO.y, loy); iy = fmaxf(iy, 0.f);
            float iz = fminf(iHI.z, hiz) - fmaxf(iLO.z, loz); iz = fmaxf(iz, 0.f);
            float inter = (ix * iy) * iz;          // ((x*y)*z) like np.prod
            float uni = iLO.w + vol - inter;       // (vol_i+vol_j)-inter
            float iou = inter / (uni + EPS);       // IEEE div
            u64 m = __ballot(iou > IOU_TR && jj > i);
            rowOr |= m;
            rowword = (lane == (w + c)) ? m : rowword;
        }
        if (inb) {
            int c = tid >> 6, l = tid & 63;
            s_b[cur ^ 1][0][c][l] = nlo.x; s_b[cur ^ 1][1][c][l] = nlo.y;
            s_b[cur ^ 1][2][c][l] = nlo.z; s_b[cur ^ 1][3][c][l] = nlo.w;
            s_b[cur ^ 1][4][c][l] = nhi.x; s_b[cur ^ 1][5][c][l] = nhi.y;
            s_b[cur ^ 1][6][c][l] = nhi.z;
        }
        __syncthreads();
    }

    if (valid && rowOr) {                         // wave-uniform branch
        Trm[(size_t)i * NW + lane] = rowword;     // coalesced 512B store
        if (lane == 0) atomicOr(&A[i >> 6], 1ull << (i & 63));
    }
}

// K3: sparse greedy scan. Producer-consumer, SB=96 (waves 1-3 stage 32 rows
// each); consumer is BATCH-PARALLEL: (A) test all 96 rows vs stable entry
// act -> 96-bit kept mask in scalars (no per-row hazard chain); (B)
// accumulate applied = OR of kept rows (independent ds_reads); (C) conflict
// check vs stable applied (ascending rows + forward-only masks => conflict
// only from earlier co-batch rows); no conflict => act &= ~applied is EXACT;
// conflict => serial redo from untouched act.
#define KB(S) (((S) < 64) ? ((km0 >> (S)) & 1ull) : ((km1 >> ((S) - 64)) & 1ull))

__global__ void __launch_bounds__(256, 1)
k_scan(const u64* __restrict__ Trm, const u64* __restrict__ A,
       const float* __restrict__ ssc, u64* __restrict__ keep) {
    __shared__ u64 s_valid[NW];
    __shared__ u16 s_nlist[4352];
    __shared__ int s_nsb;
    __shared__ u64 sbuf[2][SB][64];    // 96 KB double buffer
    const int tid = threadIdx.x;
    const int wv = tid >> 6;
    const int lane = tid & 63;

    for (int w = wv * 16; w < wv * 16 + 16; ++w) {
        float scw = ssc[w * 64 + lane];            // coalesced
        u64 m = __ballot(scw >= SCORE_TR);
        if (lane == 0) s_valid[w] = m;
    }
    __syncthreads();

    if (wv == 0) {
        u64 avA = A[lane] & s_valid[lane];  // nonempty AND valid
        int pc = __popcll(avA);
        int inc = pc;
#pragma unroll
        for (int d = 1; d < 64; d <<= 1) {
            int t = __shfl_up(inc, d, 64);
            if (lane >= d) inc += t;
        }
        int exc = inc - pc;
        int nTotal = __shfl(inc, 63, 64);
        u64 m = avA; int o = exc;
        while (m) {
            int k = __builtin_ctzll(m); m &= m - 1;
            s_nlist[o++] = (u16)(lane * 64 + k);
        }
        int nSB = (nTotal + SB - 1) / SB;
        for (int t = nTotal + lane; t < (nSB + 1) * SB && t < 4352; t += 64)
            s_nlist[t] = (u16)4095;        // sentinel (Trm row 4095 zeroed)
        if (lane == 0) s_nsb = nSB;
    }
    __syncthreads();

    const int nSB = s_nsb;
    if (wv > 0 && nSB > 0) {               // prologue: fill buffer 0
        const int base = (wv - 1) * 32;
#pragma unroll
        for (int s = 0; s < 32; ++s) {
            u32 si = (u32)s_nlist[base + s];
            sbuf[0][base + s][lane] = Trm[(size_t)si * NW + lane];
        }
    }
    u64 act = s_valid[lane];
    __syncthreads();

    for (int t = 0; t < nSB; ++t) {        // uniform bound, uniform barriers
        const int cur = t & 1;
        if (wv > 0) {                      // producers: stage super-batch t+1
            const int base = (wv - 1) * 32;
            const int off = (t + 1) * SB + base;
#pragma unroll
            for (int s = 0; s < 32; ++s) {
                u32 si = (u32)s_nlist[off + s];
                sbuf[cur ^ 1][base + s][lane] = Trm[(size_t)si * NW + lane];
            }
        } else {                           // consumer: batch-parallel
            const int off = t * SB;
            u64 km0 = 0ull, km1 = 0ull;
            // Phase A: test vs STABLE entry act (no update hazards)
#pragma unroll
            for (int s = 0; s < SB; ++s) {
                u32 si = (u32)s_nlist[off + s];
                u64 aw = rl64(act, (int)(si >> 6));
                u64 b = (aw >> (si & 63u)) & 1ull;
                if (s < 64) km0 |= b << s; else km1 |= b << (s - 64);
            }
            // Phase B: accumulate applied over kept rows (independent)
            u64 applied = 0ull;
#pragma unroll
            for (int s = 0; s < SB; ++s) {
                u64 m_ = 0ull - KB(s);
                applied |= sbuf[cur][s][lane] & m_;
            }
            // Phase C: conflict vs STABLE applied
            u64 cfl = 0ull;
#pragma unroll
            for (int s = 0; s < SB; ++s) {
                u32 si = (u32)s_nlist[off + s];
                u64 ab = (rl64(applied, (int)(si >> 6)) >> (si & 63u)) & 1ull;
                cfl |= ab & KB(s);
            }
            if (cfl) {                     // rare: exact serial redo
                for (int s = 0; s < SB; ++s) {
                    u32 siv = (u32)s_nlist[off + s];
                    u32 si = (u32)__builtin_amdgcn_readfirstlane((int)siv);
                    u64 row = sbuf[cur][s][lane];
                    u64 aw = rl64(act, (int)(si >> 6));
                    u64 msk = 0ull - ((aw >> (si & 63u)) & 1ull);
                    act &= ~(row & msk);
                }
            } else {
                act &= ~applied;           // parallel == serial (proven)
            }
        }
        __syncthreads();
    }
    if (wv == 0) keep[lane] = act;         // final act == keep mask
}

// K4: gated output, 16 blocks x 256 threads, coalesced (R20 exact).
__global__ void k_out(const float* __restrict__ rows,
                      const u64* __restrict__ keep,
                      float* __restrict__ out) {
    int i = blockIdx.x * 256 + threadIdx.x;
    bool kp = (keep[i >> 6] >> (i & 63)) & 1ull;
    float4 a = kp ? ((const float4*)rows)[i * 2]     : make_float4(0.f, 0.f, 0.f, 0.f);
    float4 b = kp ? ((const float4*)rows)[i * 2 + 1] : make_float4(0.f, 0.f, 0.f, 0.f);
    ((float4*)out)[i * 2]     = a;
    ((float4*)out)[i * 2 + 1] = b;
}

extern "C" void kernel_launch(void* const* d_in, const int* in_sizes, int n_in,
                              void* d_out, int out_size, void* d_ws, size_t ws_size,
                              hipStream_t stream) {
    const float* res = (const float*)d_in[0];
    float* out = (float*)d_out;

    float*  rows  = (float*)d_ws;                     // 32768 f32
    float*  ssc   = rows + N_DET * 8;                 // 4096 f32
    float4* soaLO = (float4*)(ssc + N_DET);           // 4096 float4
    float4* soaHI = soaLO + N_DET;                    // 4096 float4
    u64*    A     = (u64*)(soaHI + N_DET);            // 64 u64
    u64*    keep  = A + NW;                           // 64 u64
    u64*    Trm   = keep + NW;                        // 4096*64 u64

    k_sort<<<N_DET / 16, 256, 0, stream>>>(res, rows, ssc, soaLO, soaHI, A, Trm);
    k_sup <<<N_DET / 4, 256, 0, stream>>>(soaLO, soaHI, ssc, Trm, A);
    k_scan<<<1, 256, 0, stream>>>(Trm, A, ssc, keep);
    k_out <<<16, 256, 0, stream>>>(rows, keep, out);
}

// Round 22
// 49.252 us; speedup vs baseline: 1.4572x; 1.4572x over previous
//
#include <hip/hip_runtime.h>

typedef unsigned long long u64;
typedef unsigned int u32;
typedef unsigned short u16;

#define N_DET 4096
#define NW 64               // 4096 bits = 64 u64 words
#define IOU_TR 0.3f
#define SCORE_TR 0.1f
#define EPS 1e-9f

// ---------------------------------------------------------------------------
// ws layout (R20-exact revert):
//   rows  : 4096*8 f32    (sorted detection rows)        128 KB
//   ssc   : 4096 f32      (sorted scores, compact)        16 KB
//   soaLO : 4096 float4   (lox,loy,loz,vol)               64 KB
//   soaHI : 4096 float4   (hix,hiy,hiz,0)                 64 KB
//   A     : 64 u64        (bit i = row i nonempty)
//   keep  : 64 u64
//   Trm   : 4096*64 u64   row-major; nonempty rows written; row 4095 zeroed.
// 4 dispatches: k_sort, k_sup (LDS-tiled, 4x traffic cut), k_scan (R18
// producer-consumer SB=48, serial PR chain), k_out (16 blocks).
// LEDGER: R20 49.3 BEST — this file is its exact revert.
// Refuted: ov-branch sup (R7/R9 +17..30), edge-walk (R11), 2-row sup (R12),
// mirror scan (R14), last-block fusion (R7/R13), 1-block output (R10),
// spin-flag co-dispatch (R19 +1.6), batch-parallel consumer at SB=16 (R16
// neutral, 23% conflict) and SB=96 (R21 +22.5, ~100% conflict).
// Wins: sparse row list (R6), upper-tri (R8), float4 pack (R15), 4-deep
// prefetch (R17), producer-consumer scan (R18), LDS-tiled sup (R20).
// ---------------------------------------------------------------------------

__device__ __forceinline__ u64 rl64(u64 v, int l) {
    unsigned lo = __builtin_amdgcn_readlane((unsigned)v, l);
    unsigned hi = __builtin_amdgcn_readlane((unsigned)(v >> 32), l);
    return ((u64)hi << 32) | lo;
}

// K1: stable descending rank sort + zero A + zero Trm row 4095.
__global__ void __launch_bounds__(256) k_sort(const float* __restrict__ res,
                                              float* __restrict__ rows,
                                              float* __restrict__ ssc,
                                              float4* __restrict__ soaLO,
                                              float4* __restrict__ soaHI,
                                              u64* __restrict__ A,
                                              u64* __restrict__ Trm) {
    __shared__ float s[N_DET];
    int tid = threadIdx.x;
    if (blockIdx.x == 0) {
        if (tid < 64) A[tid] = 0ull;
        if (tid >= 64 && tid < 128)                 // sentinel row: all zeros
            Trm[(size_t)4095 * NW + (tid - 64)] = 0ull;
    }
    for (int j = tid; j < N_DET; j += 256) s[j] = res[j * 8];
    __syncthreads();
    int r = tid >> 4, c = tid & 15;
    int gi = blockIdx.x * 16 + r;
    float sc = s[gi];
    int part = 0;
    int j0 = c * 256;
    for (int j = j0; j < j0 + 256; ++j) {
        float sj = s[j];
        part += (sj > sc) || (sj == sc && j < gi);
    }
    part += __shfl_xor(part, 1, 64);
    part += __shfl_xor(part, 2, 64);
    part += __shfl_xor(part, 4, 64);
    part += __shfl_xor(part, 8, 64);
    if (c == 0) {
        int rank = part;
        float4 a = *(const float4*)(res + gi * 8);
        float4 b = *(const float4*)(res + gi * 8 + 4);
        *(float4*)(rows + rank * 8)     = a;
        *(float4*)(rows + rank * 8 + 4) = b;
        ssc[rank] = a.x;
        // a = (score, class, cx, cy); b = (cz, dx, dy, dz)
        float cx = a.z, cy = a.w, cz = b.x, dx = b.y, dy = b.z, dz = b.w;
        soaLO[rank] = make_float4(cx - dx * 0.5f, cy - dy * 0.5f,
                                  cz - dz * 0.5f, (dx * dy) * dz); // vol in .w
        soaHI[rank] = make_float4(cx + dx * 0.5f, cy + dy * 0.5f,
                                  cz + dz * 0.5f, 0.0f);
    }
}

// K2: suppression rows, LDS-TILED (R20-exact). Block = rows i0..i0+3; 256
// threads stage 4-word box chunks (double-buffered scalarized LDS); 4 waves
// share them (4x less L2 traffic); next chunk's loads issue before compute.
__global__ void __launch_bounds__(256) k_sup(const float4* __restrict__ soaLO,
                                             const float4* __restrict__ soaHI,
                                             const float* __restrict__ ssc,
                                             u64* __restrict__ Trm,
                                             u64* __restrict__ A) {
    __shared__ float s_b[2][7][4][64];   // [buf][field][word][box] 14 KB
    const int tid = threadIdx.x;
    const int wv = tid >> 6;
    const int lane = tid & 63;
    const int i0 = blockIdx.x * 4;
    const int i = i0 + wv;
    const int w0 = i0 >> 6;              // block-uniform start word
    const bool valid = ssc[i] >= SCORE_TR;   // wave-uniform (store guard)
    float4 iLO = soaLO[i];               // (lox,loy,loz,vol)
    float4 iHI = soaHI[i];               // (hix,hiy,hiz,-)
    u64 rowword = 0, rowOr = 0;

    {
        int j = w0 * 64 + tid;
        int c = tid >> 6, l = tid & 63;
        if (j < N_DET) {
            float4 lo = soaLO[j], hi = soaHI[j];
            s_b[0][0][c][l] = lo.x; s_b[0][1][c][l] = lo.y;
            s_b[0][2][c][l] = lo.z; s_b[0][3][c][l] = lo.w;
            s_b[0][4][c][l] = hi.x; s_b[0][5][c][l] = hi.y;
            s_b[0][6][c][l] = hi.z;
        }
    }
    __syncthreads();

    for (int w = w0; w < NW; w += 4) {
        const int cur = ((w - w0) >> 2) & 1;
        const int jn = (w + 4) * 64 + tid;
        const bool inb = jn < N_DET;
        float4 nlo = make_float4(0.f, 0.f, 0.f, 0.f);
        float4 nhi = make_float4(0.f, 0.f, 0.f, 0.f);
        if (inb) { nlo = soaLO[jn]; nhi = soaHI[jn]; }

        const int nc = (NW - w < 4) ? (NW - w) : 4;
        for (int c = 0; c < nc; ++c) {   // block-uniform bound
            int jj = (w + c) * 64 + lane;
            float lox = s_b[cur][0][c][lane], loy = s_b[cur][1][c][lane];
            float loz = s_b[cur][2][c][lane], vol = s_b[cur][3][c][lane];
            float hix = s_b[cur][4][c][lane], hiy = s_b[cur][5][c][lane];
            float hiz = s_b[cur][6][c][lane];
            float ix = fminf(iHI.x, hix) - fmaxf(iLO.x, lox); ix = fmaxf(ix, 0.f);
            float iy = fminf(iHI.y, hiy) - fmaxf(iLO.y, loy); iy = fmaxf(iy, 0.f);
            float iz = fminf(iHI.z, hiz) - fmaxf(iLO.z, loz); iz = fmaxf(iz, 0.f);
            float inter = (ix * iy) * iz;          // ((x*y)*z) like np.prod
            float uni = iLO.w + vol - inter;       // (vol_i+vol_j)-inter
            float iou = inter / (uni + EPS);       // IEEE div
            u64 m = __ballot(iou > IOU_TR && jj > i);
            rowOr |= m;
            rowword = (lane == (w + c)) ? m : rowword;
        }
        if (inb) {
            int c = tid >> 6, l = tid & 63;
            s_b[cur ^ 1][0][c][l] = nlo.x; s_b[cur ^ 1][1][c][l] = nlo.y;
            s_b[cur ^ 1][2][c][l] = nlo.z; s_b[cur ^ 1][3][c][l] = nlo.w;
            s_b[cur ^ 1][4][c][l] = nhi.x; s_b[cur ^ 1][5][c][l] = nhi.y;
            s_b[cur ^ 1][6][c][l] = nhi.z;
        }
        __syncthreads();
    }

    if (valid && rowOr) {                         // wave-uniform branch
        Trm[(size_t)i * NW + lane] = rowword;     // coalesced 512B store
        if (lane == 0) atomicOr(&A[i >> 6], 1ull << (i & 63));
    }
}

// K3: sparse greedy scan, producer-consumer (R18-exact). Waves 1-3 stage 48
// rows/super-batch into double-buffered LDS; wave 0 runs the serial PR chain.
__global__ void __launch_bounds__(256, 1)
k_scan(const u64* __restrict__ Trm, const u64* __restrict__ A,
       const float* __restrict__ ssc, u64* __restrict__ keep) {
    __shared__ u64 s_valid[NW];
    __shared__ u16 s_nlist[4608];
    __shared__ int s_nsb;
    __shared__ u64 sbuf[2][48][64];    // 48 KB double buffer
    const int tid = threadIdx.x;
    const int wv = tid >> 6;
    const int lane = tid & 63;

    // valid ballots over compact scores: 4 waves x 16 words
    for (int w = wv * 16; w < wv * 16 + 16; ++w) {
        float scw = ssc[w * 64 + lane];            // coalesced
        u64 m = __ballot(scw >= SCORE_TR);
        if (lane == 0) s_valid[w] = m;
    }
    __syncthreads();

    // wave 0: build globally-sorted active-row list + sentinel padding
    if (wv == 0) {
        u64 avA = A[lane] & s_valid[lane];  // nonempty AND valid
        int pc = __popcll(avA);
        int inc = pc;
#pragma unroll
        for (int d = 1; d < 64; d <<= 1) {
            int t = __shfl_up(inc, d, 64);
            if (lane >= d) inc += t;
        }
        int exc = inc - pc;
        int nTotal = __shfl(inc, 63, 64);
        u64 m = avA; int o = exc;
        while (m) {
            int k = __builtin_ctzll(m); m &= m - 1;
            s_nlist[o++] = (u16)(lane * 64 + k);
        }
        int nSB = (nTotal + 47) / 48;
        for (int t = nTotal + lane; t < (nSB + 1) * 48; t += 64)
            s_nlist[t] = (u16)4095;        // sentinel (Trm row 4095 zeroed)
        if (lane == 0) s_nsb = nSB;
    }
    __syncthreads();

    const int nSB = s_nsb;
    if (wv > 0 && nSB > 0) {               // prologue: fill buffer 0
        const int base = (wv - 1) * 16;
#pragma unroll
        for (int s = 0; s < 16; ++s) {
            u32 si = (u32)s_nlist[base + s];
            sbuf[0][base + s][lane] = Trm[(size_t)si * NW + lane];
        }
    }
    u64 act = s_valid[lane];
    __syncthreads();

    for (int t = 0; t < nSB; ++t) {        // uniform bound, uniform barriers
        const int cur = t & 1;
        if (wv > 0) {                      // producers: stage super-batch t+1
            const int base = (wv - 1) * 16;
            const int off = (t + 1) * 48 + base;
#pragma unroll
            for (int s = 0; s < 16; ++s) {
                u32 si = (u32)s_nlist[off + s];
                sbuf[cur ^ 1][base + s][lane] = Trm[(size_t)si * NW + lane];
            }
        } else {                           // consumer: serial PR chain on LDS
            const int off = t * 48;
#pragma unroll
            for (int s = 0; s < 48; ++s) {
                u32 siv = (u32)s_nlist[off + s];
                u32 si = (u32)__builtin_amdgcn_readfirstlane((int)siv);
                u64 row = sbuf[cur][s][lane];
                u64 aw = rl64(act, (int)(si >> 6));
                u64 msk = 0ull - ((aw >> (si & 63u)) & 1ull);
                act &= ~(row & msk);
            }
        }
        __syncthreads();
    }
    if (wv == 0) keep[lane] = act;         // final act == keep mask
}

// K4: gated output, 16 blocks x 256 threads, coalesced (R20 exact).
__global__ void k_out(const float* __restrict__ rows,
                      const u64* __restrict__ keep,
                      float* __restrict__ out) {
    int i = blockIdx.x * 256 + threadIdx.x;
    bool kp = (keep[i >> 6] >> (i & 63)) & 1ull;
    float4 a = kp ? ((const float4*)rows)[i * 2]     : make_float4(0.f, 0.f, 0.f, 0.f);
    float4 b = kp ? ((const float4*)rows)[i * 2 + 1] : make_float4(0.f, 0.f, 0.f, 0.f);
    ((float4*)out)[i * 2]     = a;
    ((float4*)out)[i * 2 + 1] = b;
}

extern "C" void kernel_launch(void* const* d_in, const int* in_sizes, int n_in,
                              void* d_out, int out_size, void* d_ws, size_t ws_size,
                              hipStream_t stream) {
    const float* res = (const float*)d_in[0];
    float* out = (float*)d_out;

    float*  rows  = (float*)d_ws;                     // 32768 f32
    float*  ssc   = rows + N_DET * 8;                 // 4096 f32
    float4* soaLO = (float4*)(ssc + N_DET);           // 4096 float4
    float4* soaHI = soaLO + N_DET;                    // 4096 float4
    u64*    A     = (u64*)(soaHI + N_DET);            // 64 u64
    u64*    keep  = A + NW;                           // 64 u64
    u64*    Trm   = keep + NW;                        // 4096*64 u64

    k_sort<<<N_DET / 16, 256, 0, stream>>>(res, rows, ssc, soaLO, soaHI, A, Trm);
    k_sup <<<N_DET / 4, 256, 0, stream>>>(soaLO, soaHI, ssc, Trm, A);
    k_scan<<<1, 256, 0, stream>>>(Trm, A, ssc, keep);
    k_out <<<16, 256, 0, stream>>>(rows, keep, out);
}